// Round 7
// baseline (254.572 us; speedup 1.0000x reference)
//
#include <hip/hip_runtime.h>
#include <hip/hip_bf16.h>

// Problem constants (match setup_inputs): B=2, N=512, D=128, H=256.
#define BB 2
#define NN 512
#define DD 128
#define HH 256

typedef __attribute__((ext_vector_type(4))) float    f32x4;
typedef __attribute__((ext_vector_type(8))) _Float16 f16x8;  // 4 VGPRs
typedef __attribute__((ext_vector_type(4))) int      i32x4;

// VALU-pipe 16-lane reduce step (DPP).
template <int CTRL>
__device__ __forceinline__ float dpp_add(float x) {
  int s = __builtin_amdgcn_update_dpp(0, __float_as_int(x), CTRL, 0xF, 0xF, true);
  return x + __int_as_float(s);
}

// ---------------------------------------------------------------------------
// Stage 1 (+W2 prep in extra blocks):
//   hA[b,n,h] = f16(b1[h] + sum_d PhiA*W1[:D]);  hB = f16(PhiB*W1[D:])
//   W2t[col][k] = f16(W2[k][col])
// ---------------------------------------------------------------------------
#define S1_ROWS 8
#define S1_BLOCKS (2 * (BB * NN) / S1_ROWS)  // 512
__global__ __launch_bounds__(256) void stage1(
    const float* __restrict__ PhiA, const float* __restrict__ PhiB,
    const float* __restrict__ W1,  const float* __restrict__ b1,
    const float* __restrict__ W2,
    _Float16* __restrict__ hA, _Float16* __restrict__ hB,
    _Float16* __restrict__ W2t) {
  if (blockIdx.x >= S1_BLOCKS) {  // W2 transpose+cast: 8 blocks
    const int bid2 = blockIdx.x - S1_BLOCKS;       // 0..7
    const int col  = bid2 * 32 + (threadIdx.x >> 3);
    const int k0   = (threadIdx.x & 7) * 32;
#pragma unroll
    for (int j = 0; j < 32; j++)
      W2t[col * HH + k0 + j] = (_Float16)W2[(k0 + j) * HH + col];
    return;
  }
  __shared__ float phis[S1_ROWS * DD];  // 4 KB
  const int side = blockIdx.x & 1;
  const int row0 = (blockIdx.x >> 1) * S1_ROWS;
  const float* Phi = side ? PhiB : PhiA;
  const float* W   = W1 + side * DD * HH;
  ((f32x4*)phis)[threadIdx.x] =
      ((const f32x4*)(Phi + (size_t)row0 * DD))[threadIdx.x];
  __syncthreads();
  const int h = threadIdx.x;
  float acc[S1_ROWS];
#pragma unroll
  for (int i = 0; i < S1_ROWS; i++) acc[i] = 0.f;
  for (int d0 = 0; d0 < DD; d0 += 4) {
    const float w0 = W[(d0 + 0) * HH + h];
    const float w1 = W[(d0 + 1) * HH + h];
    const float w2 = W[(d0 + 2) * HH + h];
    const float w3 = W[(d0 + 3) * HH + h];
#pragma unroll
    for (int i = 0; i < S1_ROWS; i++) {
      f32x4 ph = *(const f32x4*)&phis[i * DD + d0];
      acc[i] = fmaf(ph.x, w0, acc[i]);
      acc[i] = fmaf(ph.y, w1, acc[i]);
      acc[i] = fmaf(ph.z, w2, acc[i]);
      acc[i] = fmaf(ph.w, w3, acc[i]);
    }
  }
  const float bias = side ? 0.f : b1[h];
  _Float16* o = (side ? hB : hA) + (size_t)row0 * HH + h;
#pragma unroll
  for (int i = 0; i < S1_ROWS; i++) o[i * HH] = (_Float16)(acc[i] + bias);
}

// ---------------------------------------------------------------------------
// Main fused kernel, LDS-free A-path, FAT iterations.
// Grid 256 = bb(2) x mtile(32) x nslice(4); 1 block/CU, 8 waves = 2/SIMD.
// Wave w owns cols [w*32, w*32+32). Per iter: 4 n-rows x 16 m -> 64 pairs,
// 64 MFMAs/wave in 8 independent acc chains. A-frags built in-register
// (relu(hA+hB), packed f16 VALU). Barrier once per iter (~2500 issue-cyc).
// ks=0 fragments prefetched across the barrier. Deferred coalesced store.
// ---------------------------------------------------------------------------
#define GRID_MAIN 256
#define NPI 4
#define KITERS 32

__global__ __launch_bounds__(512, 2) void pairmlp(
    const _Float16* __restrict__ hA, const _Float16* __restrict__ hB,
    const _Float16* __restrict__ W2t, const float* __restrict__ b2,
    const float* __restrict__ W3, const float* __restrict__ b3,
    float* __restrict__ out) {
  __shared__ float red[2][8][64];  // per-wave partials, dbuf by iter parity

  const int tid  = threadIdx.x;
  const int lane = tid & 63;
  const int w    = tid >> 6;   // wave 0..7
  const int g    = lane >> 4;  // 0..3 (k-subgroup / D-row group)
  const int lr   = lane & 15;  // A-row (m) / B-col / D-col within 16-tile
  const int bid  = blockIdx.x;
  const int bb = bid >> 7;             // batch
  const int m0 = ((bid >> 2) & 31) * 16;
  const int ns = bid & 3;              // n-slice: rows ns*128 .. ns*128+127

  // ---- persistent W2 fragments: 8 ks x 2 ct = 64 VGPRs ----
  f16x8 breg[8][2];
#pragma unroll
  for (int ks = 0; ks < 8; ks++)
#pragma unroll
    for (int ct = 0; ct < 2; ct++) {
      const int col = w * 32 + ct * 16 + lr;
      breg[ks][ct] =
          *reinterpret_cast<const f16x8*>(&W2t[col * HH + ks * 32 + g * 8]);
    }
  // ---- loop-invariant hB fragments: 32 VGPRs ----
  f16x8 hbr[8];
  {
    const _Float16* hBp = hB + (size_t)(bb * NN + m0 + lr) * HH + g * 8;
#pragma unroll
    for (int ks = 0; ks < 8; ks++)
      hbr[ks] = *reinterpret_cast<const f16x8*>(hBp + ks * 32);
  }
  float b2v[2], w3v[2];
#pragma unroll
  for (int ct = 0; ct < 2; ct++) {
    const int col = w * 32 + ct * 16 + lr;
    b2v[ct] = b2[col];
    w3v[ct] = W3[col];
  }
  const float b3v = b3[0];

  // hA fragment base for this lane (lr-independent -> L1 broadcast)
  const _Float16* hAn = hA + (size_t)(bb * NN + ns * 128) * HH + g * 8;
  const f16x8 zero8 = {};

  // prefetch ks=0 fragments for iter 0 (held across barriers)
  f16x8 pf[NPI];
#pragma unroll
  for (int n = 0; n < NPI; n++)
    pf[n] = *reinterpret_cast<const f16x8*>(hAn + (size_t)n * HH);

  for (int k = 0; k < KITERS; k++) {
    const int cur = k & 1;
    __syncthreads();  // seals red[cur^1] from iter k-1; WAR on red[cur]

    // deferred store of iter k-1's 64 outputs
    if (k > 0 && tid < 64) {
      const int pb = cur ^ 1;
      float v = b3v;
#pragma unroll
      for (int ww = 0; ww < 8; ww++) v += red[pb][ww][tid];
      const int n = ns * 128 + NPI * (k - 1) + (tid >> 4);
      out[(size_t)(bb * NN + n) * NN + m0 + (tid & 15)] = v;
    }

    const _Float16* hAk = hAn + (size_t)(NPI * k) * HH;
    f32x4 acc[NPI][2];
#pragma unroll
    for (int n = 0; n < NPI; n++) {
      acc[n][0] = (f32x4){0.f, 0.f, 0.f, 0.f};
      acc[n][1] = (f32x4){0.f, 0.f, 0.f, 0.f};
    }
    // ks = 0 from prefetch
#pragma unroll
    for (int n = 0; n < NPI; n++) {
      f16x8 af = __builtin_elementwise_max(pf[n] + hbr[0], zero8);
      acc[n][0] = __builtin_amdgcn_mfma_f32_16x16x32_f16(af, breg[0][0], acc[n][0], 0, 0, 0);
      acc[n][1] = __builtin_amdgcn_mfma_f32_16x16x32_f16(af, breg[0][1], acc[n][1], 0, 0, 0);
    }
    // ks = 1..7
#pragma unroll
    for (int ks = 1; ks < 8; ks++)
#pragma unroll
      for (int n = 0; n < NPI; n++) {
        f16x8 ha = *reinterpret_cast<const f16x8*>(hAk + (size_t)n * HH + ks * 32);
        f16x8 af = __builtin_elementwise_max(ha + hbr[ks], zero8);
        acc[n][0] = __builtin_amdgcn_mfma_f32_16x16x32_f16(af, breg[ks][0], acc[n][0], 0, 0, 0);
        acc[n][1] = __builtin_amdgcn_mfma_f32_16x16x32_f16(af, breg[ks][1], acc[n][1], 0, 0, 0);
      }

    // prefetch ks=0 for iter k+1 (in flight across epilogue + barrier)
    if (k < KITERS - 1) {
      const _Float16* hAnx = hAn + (size_t)(NPI * (k + 1)) * HH;
#pragma unroll
      for (int n = 0; n < NPI; n++)
        pf[n] = *reinterpret_cast<const f16x8*>(hAnx + (size_t)n * HH);
    }

    // ---- epilogue: relu(.+b2)*w3, DPP 16-lane col-reduce, red[cur] ----
#pragma unroll
    for (int n = 0; n < NPI; n++)
#pragma unroll
      for (int r = 0; r < 4; r++) {
        float s = fmaxf(acc[n][0][r] + b2v[0], 0.f) * w3v[0];
        s = fmaf(fmaxf(acc[n][1][r] + b2v[1], 0.f), w3v[1], s);
        s = dpp_add<0xB1>(s);    // + lane^1
        s = dpp_add<0x4E>(s);    // + lane^2
        s = dpp_add<0x141>(s);   // + other quad (row_half_mirror)
        s = dpp_add<0x140>(s);   // + other 8-group (row_mirror)
        if (lr == 0) red[cur][w][n * 16 + g * 4 + r] = s;
      }
  }

  // tail: store the last iter's outputs
  __syncthreads();
  if (tid < 64) {
    const int pb = (KITERS - 1) & 1;
    float v = b3v;
#pragma unroll
    for (int ww = 0; ww < 8; ww++) v += red[pb][ww][tid];
    const int n = ns * 128 + NPI * (KITERS - 1) + (tid >> 4);
    out[(size_t)(bb * NN + n) * NN + m0 + (tid & 15)] = v;
  }
}

// ---------------------------------------------------------------------------
extern "C" void kernel_launch(void* const* d_in, const int* in_sizes, int n_in,
                              void* d_out, int out_size, void* d_ws, size_t ws_size,
                              hipStream_t stream) {
  const float* PhiA = (const float*)d_in[0];
  const float* PhiB = (const float*)d_in[1];
  const float* W1   = (const float*)d_in[2];
  const float* b1   = (const float*)d_in[3];
  const float* W2   = (const float*)d_in[4];
  const float* b2   = (const float*)d_in[5];
  const float* W3   = (const float*)d_in[6];
  const float* b3   = (const float*)d_in[7];
  float* out = (float*)d_out;

  char* ws = (char*)d_ws;
  _Float16* hA  = (_Float16*)ws;                    // 512 KB
  _Float16* hB  = (_Float16*)(ws + (512u << 10));   // 512 KB
  _Float16* W2t = (_Float16*)(ws + (1024u << 10));  // 128 KB

  hipLaunchKernelGGL(stage1, dim3(S1_BLOCKS + 8), dim3(256), 0, stream,
                     PhiA, PhiB, W1, b1, W2, hA, hB, W2t);
  hipLaunchKernelGGL(pairmlp, dim3(GRID_MAIN), dim3(512), 0, stream,
                     hA, hB, W2t, b2, W3, b3, out);
}

// Round 10
// 223.106 us; speedup vs baseline: 1.1410x; 1.1410x over previous
//
#include <hip/hip_runtime.h>
#include <hip/hip_bf16.h>

// Problem constants (match setup_inputs): B=2, N=512, D=128, H=256.
#define BB 2
#define NN 512
#define DD 128
#define HH 256

typedef __attribute__((ext_vector_type(4))) float    f32x4;
typedef __attribute__((ext_vector_type(8))) _Float16 f16x8;  // 4 VGPRs
typedef __attribute__((ext_vector_type(4))) int      i32x4;

union F16x8 { f16x8 v; i32x4 i; };

// ---------------------------------------------------------------------------
// Stage 1 (+W2 prep in extra blocks):
//   hA[b,n,h] = f16(b1[h] + sum_d PhiA*W1[:D]);  hB = f16(PhiB*W1[D:])
//   W2t[col][k] = f16(W2[k][col])
// 2 rows/block -> 1024 blocks (4/CU, 16 waves/CU) for latency hiding.
// ---------------------------------------------------------------------------
#define S1_ROWS 2
#define S1_BLOCKS (2 * (BB * NN) / S1_ROWS)  // 1024
__global__ __launch_bounds__(256) void stage1(
    const float* __restrict__ PhiA, const float* __restrict__ PhiB,
    const float* __restrict__ W1,  const float* __restrict__ b1,
    const float* __restrict__ W2,
    _Float16* __restrict__ hA, _Float16* __restrict__ hB,
    _Float16* __restrict__ W2t) {
  if (blockIdx.x >= S1_BLOCKS) {  // W2 transpose+cast: 8 blocks
    const int bid2 = blockIdx.x - S1_BLOCKS;       // 0..7
    const int col  = bid2 * 32 + (threadIdx.x >> 3);
    const int k0   = (threadIdx.x & 7) * 32;
#pragma unroll
    for (int j = 0; j < 32; j++)
      W2t[col * HH + k0 + j] = (_Float16)W2[(k0 + j) * HH + col];
    return;
  }
  __shared__ float phis[S1_ROWS * DD];  // 1 KB
  const int side = blockIdx.x & 1;
  const int row0 = (blockIdx.x >> 1) * S1_ROWS;
  const float* Phi = side ? PhiB : PhiA;
  const float* W   = W1 + side * DD * HH;
  if (threadIdx.x < (S1_ROWS * DD) / 4)
    ((f32x4*)phis)[threadIdx.x] =
        ((const f32x4*)(Phi + (size_t)row0 * DD))[threadIdx.x];
  __syncthreads();
  const int h = threadIdx.x;
  float acc0 = 0.f, acc1 = 0.f;
#pragma unroll
  for (int d0 = 0; d0 < DD; d0 += 8) {
    float wv[8];
#pragma unroll
    for (int j = 0; j < 8; j++) wv[j] = W[(d0 + j) * HH + h];
    f32x4 p0a = *(const f32x4*)&phis[d0];
    f32x4 p0b = *(const f32x4*)&phis[d0 + 4];
    f32x4 p1a = *(const f32x4*)&phis[DD + d0];
    f32x4 p1b = *(const f32x4*)&phis[DD + d0 + 4];
    acc0 = fmaf(p0a.x, wv[0], acc0); acc0 = fmaf(p0a.y, wv[1], acc0);
    acc0 = fmaf(p0a.z, wv[2], acc0); acc0 = fmaf(p0a.w, wv[3], acc0);
    acc0 = fmaf(p0b.x, wv[4], acc0); acc0 = fmaf(p0b.y, wv[5], acc0);
    acc0 = fmaf(p0b.z, wv[6], acc0); acc0 = fmaf(p0b.w, wv[7], acc0);
    acc1 = fmaf(p1a.x, wv[0], acc1); acc1 = fmaf(p1a.y, wv[1], acc1);
    acc1 = fmaf(p1a.z, wv[2], acc1); acc1 = fmaf(p1a.w, wv[3], acc1);
    acc1 = fmaf(p1b.x, wv[4], acc1); acc1 = fmaf(p1b.y, wv[5], acc1);
    acc1 = fmaf(p1b.z, wv[6], acc1); acc1 = fmaf(p1b.w, wv[7], acc1);
  }
  const float bias = side ? 0.f : b1[h];
  _Float16* o = (side ? hB : hA) + (size_t)row0 * HH + h;
  o[0]  = (_Float16)(acc0 + bias);
  o[HH] = (_Float16)(acc1 + bias);
}

// ---------------------------------------------------------------------------
// Main fused kernel (R5 skeleton + swapped-operand MFMA epilogue).
// 512 threads = 8 waves; wave w owns cols [w*32, w*32+32).
// MFMA computes D[w2col][pair] = mfma(breg(W2)=A, h1-frag=B): lane holds 8
// cols of ITS OWN pair -> layer-3 reduce = in-lane fma chain + shfl_xor(16,32).
// relu(x+b2)*w3 = max(x,-b2)*w3 + b2*w3 (Kc const per lane).
// ---------------------------------------------------------------------------
#define GRID_MAIN 512
#define KITERS 32

__global__ __launch_bounds__(512, 4) void pairmlp(
    const _Float16* __restrict__ hA, const _Float16* __restrict__ hB,
    const _Float16* __restrict__ W2t, const float* __restrict__ b2,
    const float* __restrict__ W3, const float* __restrict__ b3,
    float* __restrict__ out) {
  __shared__ __align__(16) short h1[2][32 * 256];  // 2 x 16 KB, swizzled f16
  __shared__ float red[2][8][32];                  // partials, dbuf by parity

  const int tid  = threadIdx.x;
  const int lane = tid & 63;
  const int w    = tid >> 6;   // wave 0..7
  const int g    = lane >> 4;  // 0..3
  const int lr   = lane & 15;
  const int bid  = blockIdx.x;
  const int bb    = bid >> 8;               // batch
  const int m0    = ((bid >> 3) & 31) * 16; // fixed per block
  const int nbase = bid & 7;                // 0..7

  // ---- persistent W2 fragments (A-operand): 8 ks x 2 ct = 64 VGPRs ----
  f16x8 breg[8][2];
#pragma unroll
  for (int ks = 0; ks < 8; ks++)
#pragma unroll
    for (int ct = 0; ct < 2; ct++) {
      const int col = w * 32 + ct * 16 + lr;
      breg[ks][ct] =
          *reinterpret_cast<const f16x8*>(&W2t[col * HH + ks * 32 + g * 8]);
    }
  // ---- per-lane epilogue constants: this lane's 8 w2-cols ----
  float nb2[2][4], w3v[2][4];
  float Kc = 0.f;
#pragma unroll
  for (int ct = 0; ct < 2; ct++)
#pragma unroll
    for (int r = 0; r < 4; r++) {
      const int col = w * 32 + ct * 16 + g * 4 + r;
      const float bv = b2[col], wv = W3[col];
      nb2[ct][r] = -bv;
      w3v[ct][r] = wv;
      Kc = fmaf(bv, wv, Kc);
    }
  const float b3v = b3[0];

  const int p  = tid >> 4;  // 0..31: pair row for construction
  const int c4 = tid & 15;  // k-chunk of 16

  // ---- loop-invariant hB chunk (f16, 8 VGPRs) ----
  F16x8 hbr[2];
  {
    const _Float16* hBp = hB + ((size_t)(bb * NN + m0 + (p & 15))) * HH + c4 * 16;
#pragma unroll
    for (int q = 0; q < 2; q++)
      hbr[q].v = *reinterpret_cast<const f16x8*>(hBp + q * 8);
  }
  const _Float16* hAbase = hA + ((size_t)(bb * NN + (p >> 4))) * HH + c4 * 16;

  auto loadA = [&](int n0, F16x8* av) {
    const _Float16* hAp = hAbase + (size_t)n0 * HH;
#pragma unroll
    for (int q = 0; q < 2; q++)
      av[q].v = *reinterpret_cast<const f16x8*>(hAp + q * 8);
  };
  auto build = [&](const F16x8* av, int buf) {
    const f16x8 zero8 = {};
#pragma unroll
    for (int q = 0; q < 2; q++) {
      F16x8 r;
      r.v = __builtin_elementwise_max(av[q].v + hbr[q].v, zero8);
      const int addr = (p * 512 + c4 * 32 + q * 16) ^ ((p & 7) << 4);
      *reinterpret_cast<i32x4*>(reinterpret_cast<char*>(h1[buf]) + addr) = r.i;
    }
  };

  // prologue: construct tile k=0 into buffer 0
  {
    F16x8 av[2];
    loadA(2 * nbase, av);
    build(av, 0);
  }

  for (int k = 0; k < KITERS; k++) {
    const int cur = k & 1;
    const int n0  = 2 * (nbase + 8 * k);
    __syncthreads();  // h1[cur] + red[cur^1] ready; WAR on h1[cur^1] resolved

    // issue next tile's hA loads early (hidden under MFMA)
    F16x8 av[2];
    if (k < KITERS - 1) loadA(n0 + 16, av);

    // store previous iter's reduced outputs (ordered by the barrier above)
    if (k > 0 && tid < 32) {
      const int pb = cur ^ 1;
      float v = b3v;
#pragma unroll
      for (int ww = 0; ww < 8; ww++) v += red[pb][ww][tid];
      const int n = (n0 - 16) + (tid >> 4);
      out[((size_t)(bb * NN + n)) * NN + m0 + (tid & 15)] = v;
    }

    // ---- MFMA (swapped operands): D[w2col][pair] ----
    f32x4 acc[2][2];
#pragma unroll
    for (int rt = 0; rt < 2; rt++)
#pragma unroll
      for (int ct = 0; ct < 2; ct++) acc[rt][ct] = (f32x4){0.f, 0.f, 0.f, 0.f};
#pragma unroll
    for (int ks = 0; ks < 8; ks++) {
      f16x8 afrag[2];
#pragma unroll
      for (int rt = 0; rt < 2; rt++) {
        const int row  = rt * 16 + lr;
        const int addr = (row * 512 + ks * 64 + g * 16) ^ ((row & 7) << 4);
        afrag[rt] = *reinterpret_cast<const f16x8*>(
            reinterpret_cast<const char*>(h1[cur]) + addr);
      }
#pragma unroll
      for (int rt = 0; rt < 2; rt++)
#pragma unroll
        for (int ct = 0; ct < 2; ct++)
          acc[rt][ct] = __builtin_amdgcn_mfma_f32_16x16x32_f16(
              breg[ks][ct], afrag[rt], acc[rt][ct], 0, 0, 0);
    }

    // construct next tile into the other buffer
    if (k < KITERS - 1) build(av, cur ^ 1);

    // ---- epilogue: per-lane 8-col fma chain + shfl_xor(16,32) reduce ----
    float s[2];
#pragma unroll
    for (int rt = 0; rt < 2; rt++) {
      float t = Kc;
#pragma unroll
      for (int ct = 0; ct < 2; ct++)
#pragma unroll
        for (int r = 0; r < 4; r++)
          t = fmaf(fmaxf(acc[rt][ct][r], nb2[ct][r]), w3v[ct][r], t);
      t += __shfl_xor(t, 16);
      t += __shfl_xor(t, 32);
      s[rt] = t;
    }
    if (lane < 16) {
      red[cur][w][lane]      = s[0];  // pair row = lane      (n = n0)
      red[cur][w][16 + lane] = s[1];  // pair row = 16 + lane (n = n0+1)
    }
  }

  // tail: store the last iter's outputs
  __syncthreads();
  if (tid < 32) {
    const int pb = (KITERS - 1) & 1;
    float v = b3v;
#pragma unroll
    for (int ww = 0; ww < 8; ww++) v += red[pb][ww][tid];
    const int n = 2 * (nbase + 8 * (KITERS - 1)) + (tid >> 4);
    out[(size_t)(bb * NN + n) * NN + m0 + (tid & 15)] = v;
  }
}

// ---------------------------------------------------------------------------
extern "C" void kernel_launch(void* const* d_in, const int* in_sizes, int n_in,
                              void* d_out, int out_size, void* d_ws, size_t ws_size,
                              hipStream_t stream) {
  const float* PhiA = (const float*)d_in[0];
  const float* PhiB = (const float*)d_in[1];
  const float* W1   = (const float*)d_in[2];
  const float* b1   = (const float*)d_in[3];
  const float* W2   = (const float*)d_in[4];
  const float* b2   = (const float*)d_in[5];
  const float* W3   = (const float*)d_in[6];
  const float* b3   = (const float*)d_in[7];
  float* out = (float*)d_out;

  char* ws = (char*)d_ws;
  _Float16* hA  = (_Float16*)ws;                    // 512 KB
  _Float16* hB  = (_Float16*)(ws + (512u << 10));   // 512 KB
  _Float16* W2t = (_Float16*)(ws + (1024u << 10));  // 128 KB

  hipLaunchKernelGGL(stage1, dim3(S1_BLOCKS + 8), dim3(256), 0, stream,
                     PhiA, PhiB, W1, b1, W2, hA, hB, W2t);
  hipLaunchKernelGGL(pairmlp, dim3(GRID_MAIN), dim3(512), 0, stream,
                     hA, hB, W2t, b2, W3, b3, out);
}

// Round 11
// 215.957 us; speedup vs baseline: 1.1788x; 1.0331x over previous
//
#include <hip/hip_runtime.h>
#include <hip/hip_bf16.h>

// Problem constants (match setup_inputs): B=2, N=512, D=128, H=256.
#define BB 2
#define NN 512
#define DD 128
#define HH 256

typedef __attribute__((ext_vector_type(4))) float    f32x4;
typedef __attribute__((ext_vector_type(8))) _Float16 f16x8;  // 4 VGPRs
typedef __attribute__((ext_vector_type(4))) int      i32x4;

union F16x8 { f16x8 v; i32x4 i; };

// ---------------------------------------------------------------------------
// Stage 1 (+W2 prep in extra blocks):
//   hA[b,n,h] = f16(b1[h] + sum_d PhiA*W1[:D]);  hB = f16(PhiB*W1[D:])
//   W2t[col][k] = f16(W2[k][col])
// ---------------------------------------------------------------------------
#define S1_ROWS 8
#define S1_BLOCKS (2 * (BB * NN) / S1_ROWS)  // 256
__global__ __launch_bounds__(256) void stage1(
    const float* __restrict__ PhiA, const float* __restrict__ PhiB,
    const float* __restrict__ W1,  const float* __restrict__ b1,
    const float* __restrict__ W2,
    _Float16* __restrict__ hA, _Float16* __restrict__ hB,
    _Float16* __restrict__ W2t) {
  if (blockIdx.x >= S1_BLOCKS) {  // W2 transpose+cast: 8 blocks
    const int bid2 = blockIdx.x - S1_BLOCKS;       // 0..7
    const int col  = bid2 * 32 + (threadIdx.x >> 3);
    const int k0   = (threadIdx.x & 7) * 32;
#pragma unroll
    for (int j = 0; j < 32; j++)
      W2t[col * HH + k0 + j] = (_Float16)W2[(k0 + j) * HH + col];
    return;
  }
  __shared__ float phis[S1_ROWS * DD];  // 4 KB
  const int side = blockIdx.x & 1;
  const int row0 = (blockIdx.x >> 1) * S1_ROWS;
  const float* Phi = side ? PhiB : PhiA;
  const float* W   = W1 + side * DD * HH;
  ((f32x4*)phis)[threadIdx.x] =
      ((const f32x4*)(Phi + (size_t)row0 * DD))[threadIdx.x];
  __syncthreads();
  const int h = threadIdx.x;
  float acc[S1_ROWS];
#pragma unroll
  for (int i = 0; i < S1_ROWS; i++) acc[i] = 0.f;
  for (int d0 = 0; d0 < DD; d0 += 4) {
    const float w0 = W[(d0 + 0) * HH + h];
    const float w1 = W[(d0 + 1) * HH + h];
    const float w2 = W[(d0 + 2) * HH + h];
    const float w3 = W[(d0 + 3) * HH + h];
#pragma unroll
    for (int i = 0; i < S1_ROWS; i++) {
      f32x4 ph = *(const f32x4*)&phis[i * DD + d0];
      acc[i] = fmaf(ph.x, w0, acc[i]);
      acc[i] = fmaf(ph.y, w1, acc[i]);
      acc[i] = fmaf(ph.z, w2, acc[i]);
      acc[i] = fmaf(ph.w, w3, acc[i]);
    }
  }
  const float bias = side ? 0.f : b1[h];
  _Float16* o = (side ? hB : hA) + (size_t)row0 * HH + h;
#pragma unroll
  for (int i = 0; i < S1_ROWS; i++) o[i * HH] = (_Float16)(acc[i] + bias);
}

// ---------------------------------------------------------------------------
// Main fused kernel (R5 skeleton + swapped-operand MFMA epilogue, spill-free).
// 512 threads = 8 waves; wave w owns cols [w*32, w*32+32).
// MFMA computes D[w2col][pair] = mfma(breg(W2)=A, h1-frag=B): lane holds 8
// cols of ITS OWN pair -> layer-3 reduce = in-lane fma chain + shfl_xor(16,32).
// relu(x+b2)*w3 = max(x,-b2)*w3 + b2*w3 (Kc). Epilogue consts PACKED f16
// (10 regs vs 18 f32 scalars: the R10 spill was exactly this delta).
// ---------------------------------------------------------------------------
#define GRID_MAIN 512
#define KITERS 32

__global__ __launch_bounds__(512, 4) void pairmlp(
    const _Float16* __restrict__ hA, const _Float16* __restrict__ hB,
    const _Float16* __restrict__ W2t, const float* __restrict__ b2,
    const float* __restrict__ W3, const float* __restrict__ b3,
    float* __restrict__ out) {
  __shared__ __align__(16) short h1[2][32 * 256];  // 2 x 16 KB, swizzled f16
  __shared__ float red[2][8][32];                  // partials, dbuf by parity

  const int tid  = threadIdx.x;
  const int lane = tid & 63;
  const int w    = tid >> 6;   // wave 0..7
  const int g    = lane >> 4;  // 0..3
  const int lr   = lane & 15;
  const int bid  = blockIdx.x;
  const int bb    = bid >> 8;               // batch
  const int m0    = ((bid >> 3) & 31) * 16; // fixed per block
  const int nbase = bid & 7;                // 0..7

  // ---- persistent W2 fragments (A-operand): 8 ks x 2 ct = 64 VGPRs ----
  f16x8 breg[8][2];
#pragma unroll
  for (int ks = 0; ks < 8; ks++)
#pragma unroll
    for (int ct = 0; ct < 2; ct++) {
      const int col = w * 32 + ct * 16 + lr;
      breg[ks][ct] =
          *reinterpret_cast<const f16x8*>(&W2t[col * HH + ks * 32 + g * 8]);
    }
  // ---- per-lane epilogue constants, PACKED f16: this lane's 8 w2-cols ----
  f16x8 nb2h, w3h;   // 4 + 4 VGPRs
  float Kc = 0.f;
#pragma unroll
  for (int i = 0; i < 8; i++) {
    const int col = w * 32 + (i >> 2) * 16 + g * 4 + (i & 3);
    const float bv = b2[col], wv = W3[col];
    nb2h[i] = (_Float16)(-bv);
    w3h[i]  = (_Float16)wv;
    Kc = fmaf(bv, wv, Kc);
  }
  const float b3v = b3[0];

  const int p  = tid >> 4;  // 0..31: pair row for construction
  const int c4 = tid & 15;  // k-chunk of 16

  // ---- loop-invariant hB chunk (f16, 8 VGPRs) ----
  F16x8 hbr[2];
  {
    const _Float16* hBp = hB + ((size_t)(bb * NN + m0 + (p & 15))) * HH + c4 * 16;
#pragma unroll
    for (int q = 0; q < 2; q++)
      hbr[q].v = *reinterpret_cast<const f16x8*>(hBp + q * 8);
  }
  const _Float16* hAbase = hA + ((size_t)(bb * NN + (p >> 4))) * HH + c4 * 16;

  auto loadA = [&](int n0, F16x8* av) {
    const _Float16* hAp = hAbase + (size_t)n0 * HH;
#pragma unroll
    for (int q = 0; q < 2; q++)
      av[q].v = *reinterpret_cast<const f16x8*>(hAp + q * 8);
  };
  auto build = [&](const F16x8* av, int buf) {
    const f16x8 zero8 = {};
#pragma unroll
    for (int q = 0; q < 2; q++) {
      F16x8 r;
      r.v = __builtin_elementwise_max(av[q].v + hbr[q].v, zero8);
      const int addr = (p * 512 + c4 * 32 + q * 16) ^ ((p & 7) << 4);
      *reinterpret_cast<i32x4*>(reinterpret_cast<char*>(h1[buf]) + addr) = r.i;
    }
  };

  // prologue: construct tile k=0 into buffer 0
  {
    F16x8 av[2];
    loadA(2 * nbase, av);
    build(av, 0);
  }

  for (int k = 0; k < KITERS; k++) {
    const int cur = k & 1;
    const int n0  = 2 * (nbase + 8 * k);
    __syncthreads();  // h1[cur] + red[cur^1] ready; WAR on h1[cur^1] resolved

    // issue next tile's hA loads early (hidden under MFMA)
    F16x8 av[2];
    if (k < KITERS - 1) loadA(n0 + 16, av);

    // store previous iter's reduced outputs (ordered by the barrier above)
    if (k > 0 && tid < 32) {
      const int pb = cur ^ 1;
      float v = b3v;
#pragma unroll
      for (int ww = 0; ww < 8; ww++) v += red[pb][ww][tid];
      const int n = (n0 - 16) + (tid >> 4);
      out[((size_t)(bb * NN + n)) * NN + m0 + (tid & 15)] = v;
    }

    // ---- MFMA (swapped operands): D[w2col][pair] ----
    f32x4 acc[2][2];
#pragma unroll
    for (int rt = 0; rt < 2; rt++)
#pragma unroll
      for (int ct = 0; ct < 2; ct++) acc[rt][ct] = (f32x4){0.f, 0.f, 0.f, 0.f};
#pragma unroll
    for (int ks = 0; ks < 8; ks++) {
      f16x8 afrag[2];
#pragma unroll
      for (int rt = 0; rt < 2; rt++) {
        const int row  = rt * 16 + lr;
        const int addr = (row * 512 + ks * 64 + g * 16) ^ ((row & 7) << 4);
        afrag[rt] = *reinterpret_cast<const f16x8*>(
            reinterpret_cast<const char*>(h1[cur]) + addr);
      }
#pragma unroll
      for (int rt = 0; rt < 2; rt++)
#pragma unroll
        for (int ct = 0; ct < 2; ct++)
          acc[rt][ct] = __builtin_amdgcn_mfma_f32_16x16x32_f16(
              breg[ks][ct], afrag[rt], acc[rt][ct], 0, 0, 0);
    }

    // construct next tile into the other buffer
    if (k < KITERS - 1) build(av, cur ^ 1);

    // ---- epilogue: per-lane 8-col fma chain + shfl_xor(16,32) reduce ----
    float s[2];
#pragma unroll
    for (int rt = 0; rt < 2; rt++) {
      float t = Kc;
#pragma unroll
      for (int ct = 0; ct < 2; ct++)
#pragma unroll
        for (int r = 0; r < 4; r++) {
          const float nb = (float)nb2h[ct * 4 + r];
          const float wv = (float)w3h[ct * 4 + r];
          t = fmaf(fmaxf(acc[rt][ct][r], nb), wv, t);
        }
      t += __shfl_xor(t, 16);
      t += __shfl_xor(t, 32);
      s[rt] = t;
    }
    if (lane < 16) {
      red[cur][w][lane]      = s[0];  // pair row = lane      (n = n0)
      red[cur][w][16 + lane] = s[1];  // pair row = 16 + lane (n = n0+1)
    }
  }

  // tail: store the last iter's outputs
  __syncthreads();
  if (tid < 32) {
    const int pb = (KITERS - 1) & 1;
    float v = b3v;
#pragma unroll
    for (int ww = 0; ww < 8; ww++) v += red[pb][ww][tid];
    const int n = 2 * (nbase + 8 * (KITERS - 1)) + (tid >> 4);
    out[(size_t)(bb * NN + n) * NN + m0 + (tid & 15)] = v;
  }
}

// ---------------------------------------------------------------------------
extern "C" void kernel_launch(void* const* d_in, const int* in_sizes, int n_in,
                              void* d_out, int out_size, void* d_ws, size_t ws_size,
                              hipStream_t stream) {
  const float* PhiA = (const float*)d_in[0];
  const float* PhiB = (const float*)d_in[1];
  const float* W1   = (const float*)d_in[2];
  const float* b1   = (const float*)d_in[3];
  const float* W2   = (const float*)d_in[4];
  const float* b2   = (const float*)d_in[5];
  const float* W3   = (const float*)d_in[6];
  const float* b3   = (const float*)d_in[7];
  float* out = (float*)d_out;

  char* ws = (char*)d_ws;
  _Float16* hA  = (_Float16*)ws;                    // 512 KB
  _Float16* hB  = (_Float16*)(ws + (512u << 10));   // 512 KB
  _Float16* W2t = (_Float16*)(ws + (1024u << 10));  // 128 KB

  hipLaunchKernelGGL(stage1, dim3(S1_BLOCKS + 8), dim3(256), 0, stream,
                     PhiA, PhiB, W1, b1, W2, hA, hB, W2t);
  hipLaunchKernelGGL(pairmlp, dim3(GRID_MAIN), dim3(512), 0, stream,
                     hA, hB, W2t, b2, W3, b3, out);
}

// Round 12
// 149.867 us; speedup vs baseline: 1.6986x; 1.4410x over previous
//
#include <hip/hip_runtime.h>
#include <hip/hip_bf16.h>

// Problem constants (match setup_inputs): B=2, N=512, D=128, H=256.
#define BB 2
#define NN 512
#define DD 128
#define HH 256

typedef __attribute__((ext_vector_type(4))) float    f32x4;
typedef __attribute__((ext_vector_type(8))) _Float16 f16x8;  // 4 VGPRs
typedef __attribute__((ext_vector_type(4))) int      i32x4;

union F16x8 { f16x8 v; i32x4 i; };

// ---------------------------------------------------------------------------
// Stage 1 (+W2 prep in extra blocks):
//   hA[b,n,h] = f16(b1[h] + sum_d PhiA*W1[:D]);  hB = f16(PhiB*W1[D:])
//   W2t[col][k] = f16(W2[k][col])
// ---------------------------------------------------------------------------
#define S1_ROWS 8
#define S1_BLOCKS (2 * (BB * NN) / S1_ROWS)  // 256
__global__ __launch_bounds__(256) void stage1(
    const float* __restrict__ PhiA, const float* __restrict__ PhiB,
    const float* __restrict__ W1,  const float* __restrict__ b1,
    const float* __restrict__ W2,
    _Float16* __restrict__ hA, _Float16* __restrict__ hB,
    _Float16* __restrict__ W2t) {
  if (blockIdx.x >= S1_BLOCKS) {  // W2 transpose+cast: 8 blocks
    const int bid2 = blockIdx.x - S1_BLOCKS;       // 0..7
    const int col  = bid2 * 32 + (threadIdx.x >> 3);
    const int k0   = (threadIdx.x & 7) * 32;
#pragma unroll
    for (int j = 0; j < 32; j++)
      W2t[col * HH + k0 + j] = (_Float16)W2[(k0 + j) * HH + col];
    return;
  }
  __shared__ float phis[S1_ROWS * DD];  // 4 KB
  const int side = blockIdx.x & 1;
  const int row0 = (blockIdx.x >> 1) * S1_ROWS;
  const float* Phi = side ? PhiB : PhiA;
  const float* W   = W1 + side * DD * HH;
  ((f32x4*)phis)[threadIdx.x] =
      ((const f32x4*)(Phi + (size_t)row0 * DD))[threadIdx.x];
  __syncthreads();
  const int h = threadIdx.x;
  float acc[S1_ROWS];
#pragma unroll
  for (int i = 0; i < S1_ROWS; i++) acc[i] = 0.f;
  for (int d0 = 0; d0 < DD; d0 += 4) {
    const float w0 = W[(d0 + 0) * HH + h];
    const float w1 = W[(d0 + 1) * HH + h];
    const float w2 = W[(d0 + 2) * HH + h];
    const float w3 = W[(d0 + 3) * HH + h];
#pragma unroll
    for (int i = 0; i < S1_ROWS; i++) {
      f32x4 ph = *(const f32x4*)&phis[i * DD + d0];
      acc[i] = fmaf(ph.x, w0, acc[i]);
      acc[i] = fmaf(ph.y, w1, acc[i]);
      acc[i] = fmaf(ph.z, w2, acc[i]);
      acc[i] = fmaf(ph.w, w3, acc[i]);
    }
  }
  const float bias = side ? 0.f : b1[h];
  _Float16* o = (side ? hB : hA) + (size_t)row0 * HH + h;
#pragma unroll
  for (int i = 0; i < S1_ROWS; i++) o[i * HH] = (_Float16)(acc[i] + bias);
}

// ---------------------------------------------------------------------------
// Main fused kernel (R11 structure; launch_bounds relaxed to kill the spill).
// 512 threads = 8 waves; wave w owns cols [w*32, w*32+32).
// MFMA computes D[w2col][pair] = mfma(breg(W2)=A, h1-frag=B): lane holds 8
// cols of ITS OWN pair -> layer-3 reduce = in-lane fma chain + shfl_xor(16,32).
// relu(x+b2)*w3 = max(x,-b2)*w3 + b2*w3 (Kc). launch_bounds(512,2): 256-reg
// cap, compiler's natural ~140-170 alloc fits -> NO scratch. 2 waves/SIMD;
// 4 indep acc chains/wave keep the MFMA pipe fed between barriers.
// ---------------------------------------------------------------------------
#define GRID_MAIN 512
#define KITERS 32

__global__ __launch_bounds__(512, 2) void pairmlp(
    const _Float16* __restrict__ hA, const _Float16* __restrict__ hB,
    const _Float16* __restrict__ W2t, const float* __restrict__ b2,
    const float* __restrict__ W3, const float* __restrict__ b3,
    float* __restrict__ out) {
  __shared__ __align__(16) short h1[2][32 * 256];  // 2 x 16 KB, swizzled f16
  __shared__ float red[2][8][32];                  // partials, dbuf by parity

  const int tid  = threadIdx.x;
  const int lane = tid & 63;
  const int w    = tid >> 6;   // wave 0..7
  const int g    = lane >> 4;  // 0..3
  const int lr   = lane & 15;
  const int bid  = blockIdx.x;
  const int bb    = bid >> 8;               // batch
  const int m0    = ((bid >> 3) & 31) * 16; // fixed per block
  const int nbase = bid & 7;                // 0..7

  // ---- persistent W2 fragments (A-operand): 8 ks x 2 ct = 64 VGPRs ----
  f16x8 breg[8][2];
#pragma unroll
  for (int ks = 0; ks < 8; ks++)
#pragma unroll
    for (int ct = 0; ct < 2; ct++) {
      const int col = w * 32 + ct * 16 + lr;
      breg[ks][ct] =
          *reinterpret_cast<const f16x8*>(&W2t[col * HH + ks * 32 + g * 8]);
    }
  // ---- per-lane epilogue constants, PACKED f16: this lane's 8 w2-cols ----
  f16x8 nb2h, w3h;   // 4 + 4 VGPRs
  float Kc = 0.f;
#pragma unroll
  for (int i = 0; i < 8; i++) {
    const int col = w * 32 + (i >> 2) * 16 + g * 4 + (i & 3);
    const float bv = b2[col], wv = W3[col];
    nb2h[i] = (_Float16)(-bv);
    w3h[i]  = (_Float16)wv;
    Kc = fmaf(bv, wv, Kc);
  }
  const float b3v = b3[0];

  const int p  = tid >> 4;  // 0..31: pair row for construction
  const int c4 = tid & 15;  // k-chunk of 16

  // ---- loop-invariant hB chunk (f16, 8 VGPRs) ----
  F16x8 hbr[2];
  {
    const _Float16* hBp = hB + ((size_t)(bb * NN + m0 + (p & 15))) * HH + c4 * 16;
#pragma unroll
    for (int q = 0; q < 2; q++)
      hbr[q].v = *reinterpret_cast<const f16x8*>(hBp + q * 8);
  }
  const _Float16* hAbase = hA + ((size_t)(bb * NN + (p >> 4))) * HH + c4 * 16;

  auto loadA = [&](int n0, F16x8* av) {
    const _Float16* hAp = hAbase + (size_t)n0 * HH;
#pragma unroll
    for (int q = 0; q < 2; q++)
      av[q].v = *reinterpret_cast<const f16x8*>(hAp + q * 8);
  };
  auto build = [&](const F16x8* av, int buf) {
    const f16x8 zero8 = {};
#pragma unroll
    for (int q = 0; q < 2; q++) {
      F16x8 r;
      r.v = __builtin_elementwise_max(av[q].v + hbr[q].v, zero8);
      const int addr = (p * 512 + c4 * 32 + q * 16) ^ ((p & 7) << 4);
      *reinterpret_cast<i32x4*>(reinterpret_cast<char*>(h1[buf]) + addr) = r.i;
    }
  };

  // prologue: construct tile k=0 into buffer 0
  {
    F16x8 av[2];
    loadA(2 * nbase, av);
    build(av, 0);
  }

  for (int k = 0; k < KITERS; k++) {
    const int cur = k & 1;
    const int n0  = 2 * (nbase + 8 * k);
    __syncthreads();  // h1[cur] + red[cur^1] ready; WAR on h1[cur^1] resolved

    // issue next tile's hA loads early (hidden under MFMA)
    F16x8 av[2];
    if (k < KITERS - 1) loadA(n0 + 16, av);

    // store previous iter's reduced outputs (ordered by the barrier above)
    if (k > 0 && tid < 32) {
      const int pb = cur ^ 1;
      float v = b3v;
#pragma unroll
      for (int ww = 0; ww < 8; ww++) v += red[pb][ww][tid];
      const int n = (n0 - 16) + (tid >> 4);
      out[((size_t)(bb * NN + n)) * NN + m0 + (tid & 15)] = v;
    }

    // ---- MFMA (swapped operands): D[w2col][pair] ----
    f32x4 acc[2][2];
#pragma unroll
    for (int rt = 0; rt < 2; rt++)
#pragma unroll
      for (int ct = 0; ct < 2; ct++) acc[rt][ct] = (f32x4){0.f, 0.f, 0.f, 0.f};
#pragma unroll
    for (int ks = 0; ks < 8; ks++) {
      f16x8 afrag[2];
#pragma unroll
      for (int rt = 0; rt < 2; rt++) {
        const int row  = rt * 16 + lr;
        const int addr = (row * 512 + ks * 64 + g * 16) ^ ((row & 7) << 4);
        afrag[rt] = *reinterpret_cast<const f16x8*>(
            reinterpret_cast<const char*>(h1[cur]) + addr);
      }
#pragma unroll
      for (int rt = 0; rt < 2; rt++)
#pragma unroll
        for (int ct = 0; ct < 2; ct++)
          acc[rt][ct] = __builtin_amdgcn_mfma_f32_16x16x32_f16(
              breg[ks][ct], afrag[rt], acc[rt][ct], 0, 0, 0);
    }

    // construct next tile into the other buffer
    if (k < KITERS - 1) build(av, cur ^ 1);

    // ---- epilogue: per-lane 8-col fma chain + shfl_xor(16,32) reduce ----
    float s[2];
#pragma unroll
    for (int rt = 0; rt < 2; rt++) {
      float t = Kc;
#pragma unroll
      for (int ct = 0; ct < 2; ct++)
#pragma unroll
        for (int r = 0; r < 4; r++) {
          const float nb = (float)nb2h[ct * 4 + r];
          const float wv = (float)w3h[ct * 4 + r];
          t = fmaf(fmaxf(acc[rt][ct][r], nb), wv, t);
        }
      t += __shfl_xor(t, 16);
      t += __shfl_xor(t, 32);
      s[rt] = t;
    }
    if (lane < 16) {
      red[cur][w][lane]      = s[0];  // pair row = lane      (n = n0)
      red[cur][w][16 + lane] = s[1];  // pair row = 16 + lane (n = n0+1)
    }
  }

  // tail: store the last iter's outputs
  __syncthreads();
  if (tid < 32) {
    const int pb = (KITERS - 1) & 1;
    float v = b3v;
#pragma unroll
    for (int ww = 0; ww < 8; ww++) v += red[pb][ww][tid];
    const int n = 2 * (nbase + 8 * (KITERS - 1)) + (tid >> 4);
    out[(size_t)(bb * NN + n) * NN + m0 + (tid & 15)] = v;
  }
}

// ---------------------------------------------------------------------------
extern "C" void kernel_launch(void* const* d_in, const int* in_sizes, int n_in,
                              void* d_out, int out_size, void* d_ws, size_t ws_size,
                              hipStream_t stream) {
  const float* PhiA = (const float*)d_in[0];
  const float* PhiB = (const float*)d_in[1];
  const float* W1   = (const float*)d_in[2];
  const float* b1   = (const float*)d_in[3];
  const float* W2   = (const float*)d_in[4];
  const float* b2   = (const float*)d_in[5];
  const float* W3   = (const float*)d_in[6];
  const float* b3   = (const float*)d_in[7];
  float* out = (float*)d_out;

  char* ws = (char*)d_ws;
  _Float16* hA  = (_Float16*)ws;                    // 512 KB
  _Float16* hB  = (_Float16*)(ws + (512u << 10));   // 512 KB
  _Float16* W2t = (_Float16*)(ws + (1024u << 10));  // 128 KB

  hipLaunchKernelGGL(stage1, dim3(S1_BLOCKS + 8), dim3(256), 0, stream,
                     PhiA, PhiB, W1, b1, W2, hA, hB, W2t);
  hipLaunchKernelGGL(pairmlp, dim3(GRID_MAIN), dim3(512), 0, stream,
                     hA, hB, W2t, b2, W3, b3, out);
}